// Round 2
// baseline (24437.027 us; speedup 1.0000x reference)
//
#include <hip/hip_runtime.h>
#include <hip/hip_bf16.h>
#include <math.h>

#define C 320
#define P 32
#define H 8
#define DH 40
#define RSEL 8
#define NINE 9
#define NTOK 16384
#define TPW 16

// ---------------------------------------------------------------------------
// K0b: rope tables for positions 0..8, pair index 0..159 (fp32 storage)
// ---------------------------------------------------------------------------
__global__ __launch_bounds__(256) void k_tables(float* __restrict__ cosT,
                                                float* __restrict__ sinT) {
  int e = blockIdx.x * 256 + threadIdx.x;
  if (e >= NINE * 160) return;
  int l = e / 160, ii = e - l * 160;
  double inv = pow(10000.0, -(double)(2 * ii) / (double)C);
  double ang = (double)l * inv;
  cosT[e] = (float)cos(ang);
  sinT[e] = (float)sin(ang);
}

// ---------------------------------------------------------------------------
// K0c: WkT[cp][b] = Wk[b][cp]  (transpose for contiguous column access)
// ---------------------------------------------------------------------------
__global__ __launch_bounds__(256) void k_wkT(const float* __restrict__ Wk,
                                             float* __restrict__ WkT) {
  int o = blockIdx.x * 256 + threadIdx.x;
  if (o >= C * C) return;
  int cp = o / C, b = o - cp * C;
  WkT[o] = Wk[(size_t)b * C + cp];
}

// ---------------------------------------------------------------------------
// K1b: Q = X @ Wq  (fp32), M=16384 N=320 K=320. grid (256,5), 64x64 tile BK=16
// ---------------------------------------------------------------------------
__global__ __launch_bounds__(256) void k_qgemm(const float* __restrict__ X,
                                               const float* __restrict__ W,
                                               float* __restrict__ Qo) {
  __shared__ float As[16][66];
  __shared__ float Bs[16][64];
  int tid = threadIdx.x;
  int m0 = blockIdx.x * 64, n0 = blockIdx.y * 64;
  int tm = (tid >> 4) << 2, tn = (tid & 15) << 2;
  int mA = tid >> 2, k4 = (tid & 3) << 2;
  int kB = tid >> 6, nB = tid & 63;
  float acc[4][4] = {};
  for (int k0 = 0; k0 < C; k0 += 16) {
    float4 av = *(const float4*)(X + (size_t)(m0 + mA) * C + k0 + k4);
    As[k4 + 0][mA] = av.x; As[k4 + 1][mA] = av.y; As[k4 + 2][mA] = av.z; As[k4 + 3][mA] = av.w;
#pragma unroll
    for (int j = 0; j < 4; ++j)
      Bs[kB + 4 * j][nB] = W[(size_t)(k0 + kB + 4 * j) * C + n0 + nB];
    __syncthreads();
#pragma unroll
    for (int kk = 0; kk < 16; ++kk) {
      float a0 = As[kk][tm + 0], a1 = As[kk][tm + 1], a2 = As[kk][tm + 2], a3 = As[kk][tm + 3];
      float b0 = Bs[kk][tn + 0], b1 = Bs[kk][tn + 1], b2 = Bs[kk][tn + 2], b3 = Bs[kk][tn + 3];
      acc[0][0] += a0 * b0; acc[0][1] += a0 * b1; acc[0][2] += a0 * b2; acc[0][3] += a0 * b3;
      acc[1][0] += a1 * b0; acc[1][1] += a1 * b1; acc[1][2] += a1 * b2; acc[1][3] += a1 * b3;
      acc[2][0] += a2 * b0; acc[2][1] += a2 * b1; acc[2][2] += a2 * b2; acc[2][3] += a2 * b3;
      acc[3][0] += a3 * b0; acc[3][1] += a3 * b1; acc[3][2] += a3 * b2; acc[3][3] += a3 * b3;
    }
    __syncthreads();
  }
#pragma unroll
  for (int i = 0; i < 4; ++i)
#pragma unroll
    for (int j = 0; j < 4; ++j)
      Qo[(size_t)(m0 + tm + i) * C + n0 + tn + j] = acc[i][j];
}

// ---------------------------------------------------------------------------
// K2: literal fp32 score path (mimics reference arithmetic structure):
//   k_past[p][cp] = sum_b row_p[b]*Wk[b][cp]  (fp32, blocked-4 partials)
//   score[p] = sum_cp q[cp]*k_past[p][cp]     (fp32)
// then exact top-8 (desc value, lower index on tie). grid 16384, 256 thr.
// thread t -> (p = t>>3, l8 = t&7); lane handles cp = 8j+l8, j=0..39,
// register-blocking all 40 accumulators so each row element is read once.
// ---------------------------------------------------------------------------
__global__ __launch_bounds__(256) void k_scoresel(const float* __restrict__ cached,
                                                  const float* __restrict__ Qm,
                                                  const float* __restrict__ WkT,
                                                  int* __restrict__ idxb) {
  __shared__ float sRows[P][328];  // +8 pad: 2-way max bank aliasing
  __shared__ float sQ[C];
  __shared__ float sS[P];
  __shared__ int sIdx[RSEL];
  int n = blockIdx.x;
  int tid = threadIdx.x;
  for (int c = tid; c < C; c += 256) sQ[c] = Qm[(size_t)n * C + c];
  for (int e = tid; e < P * C; e += 256) {
    int p = e / C, b = e - p * C;
    sRows[p][b] = cached[((size_t)n * P + p) * C + b];
  }
  __syncthreads();
  int p = tid >> 3, l8 = tid & 7;
  float kp[40];
#pragma unroll
  for (int j = 0; j < 40; ++j) kp[j] = 0.f;
  const float* wbase = WkT + (size_t)l8 * C;
  for (int b = 0; b < C; b += 4) {
    float4 r = *(const float4*)&sRows[p][b];
#pragma unroll
    for (int j = 0; j < 40; ++j) {
      float4 w = *(const float4*)(wbase + (size_t)j * 8 * C + b);
      kp[j] = fmaf(r.x, w.x, fmaf(r.y, w.y, fmaf(r.z, w.z, fmaf(r.w, w.w, kp[j]))));
    }
  }
  float sc = 0.f;
#pragma unroll
  for (int j = 0; j < 40; ++j) sc = fmaf(sQ[8 * j + l8], kp[j], sc);
  sc += __shfl_down(sc, 4, 8);
  sc += __shfl_down(sc, 2, 8);
  sc += __shfl_down(sc, 1, 8);
  if (l8 == 0) sS[p] = sc;
  __syncthreads();
  if (tid < 64) {
    float s = (tid < P) ? sS[tid] : -1e30f;
    int pi = (tid < P) ? tid : 9999;
    for (int r = 0; r < RSEL; ++r) {
      float bs = s; int bp = pi;
      for (int d = 1; d < 64; d <<= 1) {
        float os = __shfl_xor(bs, d);
        int op = __shfl_xor(bp, d);
        if (os > bs || (os == bs && op < bp)) { bs = os; bp = op; }
      }
      if (tid == 0) sIdx[r] = bp;
      if (pi == bp) s = -1e30f;
    }
  }
  __syncthreads();
  if (tid < RSEL) idxb[(size_t)n * RSEL + tid] = sIdx[tid];
}

// ---------------------------------------------------------------------------
// K3: Ksel = gather(rows) @ Wk -> bf16.  M=16384*9 rows: row l<8 = selected
// cached row, l==8 = x (k_now).  grid (2304, 5), 64x64 tile BK=16
// ---------------------------------------------------------------------------
__global__ __launch_bounds__(256) void k_kselgemm(const float* __restrict__ X,
                                                  const float* __restrict__ cached,
                                                  const int* __restrict__ idxb,
                                                  const float* __restrict__ Wk,
                                                  __hip_bfloat16* __restrict__ Ksel) {
  __shared__ float As[16][66];
  __shared__ float Bs[16][64];
  __shared__ const float* srow[64];
  int tid = threadIdx.x;
  int m0 = blockIdx.x * 64, n0 = blockIdx.y * 64;
  if (tid < 64) {
    int m = m0 + tid;
    int n = m / NINE, l = m - n * NINE;
    srow[tid] = (l < RSEL)
        ? cached + ((size_t)n * P + idxb[(size_t)n * RSEL + l]) * C
        : X + (size_t)n * C;
  }
  __syncthreads();
  int tm = (tid >> 4) << 2, tn = (tid & 15) << 2;
  int mA = tid >> 2, k4 = (tid & 3) << 2;
  int kB = tid >> 6, nB = tid & 63;
  float acc[4][4] = {};
  for (int k0 = 0; k0 < C; k0 += 16) {
    float4 av = *(const float4*)(srow[mA] + k0 + k4);
    As[k4 + 0][mA] = av.x; As[k4 + 1][mA] = av.y; As[k4 + 2][mA] = av.z; As[k4 + 3][mA] = av.w;
#pragma unroll
    for (int j = 0; j < 4; ++j)
      Bs[kB + 4 * j][nB] = Wk[(size_t)(k0 + kB + 4 * j) * C + n0 + nB];
    __syncthreads();
#pragma unroll
    for (int kk = 0; kk < 16; ++kk) {
      float a0 = As[kk][tm + 0], a1 = As[kk][tm + 1], a2 = As[kk][tm + 2], a3 = As[kk][tm + 3];
      float b0 = Bs[kk][tn + 0], b1 = Bs[kk][tn + 1], b2 = Bs[kk][tn + 2], b3 = Bs[kk][tn + 3];
      acc[0][0] += a0 * b0; acc[0][1] += a0 * b1; acc[0][2] += a0 * b2; acc[0][3] += a0 * b3;
      acc[1][0] += a1 * b0; acc[1][1] += a1 * b1; acc[1][2] += a1 * b2; acc[1][3] += a1 * b3;
      acc[2][0] += a2 * b0; acc[2][1] += a2 * b1; acc[2][2] += a2 * b2; acc[2][3] += a2 * b3;
      acc[3][0] += a3 * b0; acc[3][1] += a3 * b1; acc[3][2] += a3 * b2; acc[3][3] += a3 * b3;
    }
    __syncthreads();
  }
#pragma unroll
  for (int i = 0; i < 4; ++i)
#pragma unroll
    for (int j = 0; j < 4; ++j)
      Ksel[(size_t)(m0 + tm + i) * C + n0 + tn + j] = __float2bfloat16(acc[i][j]);
}

// ---------------------------------------------------------------------------
// K4a: per-token attention: rope(Ksel), logits, softmax, z = sum_l w*row_l
// writes Z bf16 [n][h][c].  grid 16384, 256 threads
// ---------------------------------------------------------------------------
__global__ __launch_bounds__(256) void k_attn(const float* __restrict__ X,
                                              const float* __restrict__ cached,
                                              const float* __restrict__ Qm,
                                              const __hip_bfloat16* __restrict__ Ksel,
                                              const int* __restrict__ idxb,
                                              const float* __restrict__ cosT,
                                              const float* __restrict__ sinT,
                                              __hip_bfloat16* __restrict__ Z) {
  __shared__ float sK[NINE * C];
  __shared__ float sRows[NINE * C];
  __shared__ float sQ[C];
  __shared__ float sLog[H * NINE];
  __shared__ float sWgt[H * NINE];
  __shared__ int sIdx[RSEL];
  int n = blockIdx.x;
  int tid = threadIdx.x;
  if (tid < RSEL) sIdx[tid] = idxb[(size_t)n * RSEL + tid];
  for (int c = tid; c < C; c += 256) sQ[c] = Qm[(size_t)n * C + c];
  __syncthreads();
  for (int e = tid; e < NINE * C; e += 256) {
    int l = e / C, c = e - l * C;
    sK[e] = __bfloat162float(Ksel[((size_t)n * NINE + l) * C + c]);
    const float* src = (l < RSEL)
        ? cached + ((size_t)n * P + sIdx[l]) * C
        : X + (size_t)n * C;
    sRows[e] = src[c];
  }
  __syncthreads();
  for (int e = tid; e < NINE * 160; e += 256) {
    int l = e / 160, ii = e - l * 160;
    float cs = cosT[e], sn = sinT[e];
    float ev = sK[l * C + 2 * ii], ov = sK[l * C + 2 * ii + 1];
    sK[l * C + 2 * ii]     = ev * cs - ov * sn;
    sK[l * C + 2 * ii + 1] = ev * sn + ov * cs;
  }
  __syncthreads();
  if (tid < H * NINE) {
    int h = tid / NINE, l = tid - h * NINE;
    const float* qh = sQ + h * DH;
    const float* kh = sK + l * C + h * DH;
    float a = 0.f;
    for (int d = 0; d < DH; ++d) a += qh[d] * kh[d];
    sLog[tid] = a * 0.15811388300841897f; // 40^-0.5
  }
  __syncthreads();
  if (tid < H) {
    float m = -1e30f;
    for (int l = 0; l < NINE; ++l) m = fmaxf(m, sLog[tid * NINE + l]);
    float w[NINE];
    float s = 0.f;
    for (int l = 0; l < NINE; ++l) { w[l] = expf(sLog[tid * NINE + l] - m); s += w[l]; }
    float inv = 1.f / s;
    for (int l = 0; l < NINE; ++l) sWgt[tid * NINE + l] = w[l] * inv;
  }
  __syncthreads();
  for (int o = tid; o < H * C; o += 256) {
    int h = o / C, c = o - h * C;
    float a = 0.f;
#pragma unroll
    for (int l = 0; l < NINE; ++l) a += sWgt[h * NINE + l] * sRows[l * C + c];
    Z[(size_t)n * (H * C) + o] = __float2bfloat16(a);
  }
}

// ---------------------------------------------------------------------------
// K4b: ctx[i][cp] = sum_c Z[i][h(cp)][c]*Wv[c][cp]; out = ctx@Wo + bo
// grid 1024 (16 tokens each), 256 threads; micro-tile 4 tokens x 5 cols
// ---------------------------------------------------------------------------
__global__ __launch_bounds__(256) void k_ctxout(const __hip_bfloat16* __restrict__ Z,
                                                const float* __restrict__ Wv,
                                                const float* __restrict__ Wo,
                                                const float* __restrict__ bo,
                                                float* __restrict__ out) {
  __shared__ float sWtile[16 * C];
  __shared__ __hip_bfloat16 sZt[TPW * H * 16];
  __shared__ float sCtx[TPW * C];
  int tid = threadIdx.x;
  size_t nbase = (size_t)blockIdx.x * TPW;
  int i0 = (tid >> 6) << 2;
  int tc = tid & 63;
  int cp0 = tc * 5;
  int h1 = cp0 / DH;
  float acc[4][5] = {};
  for (int c0 = 0; c0 < C; c0 += 16) {
    for (int e = tid; e < 16 * C; e += 256)
      sWtile[e] = Wv[(size_t)(c0 + e / C) * C + (e - (e / C) * C)];
    for (int e = tid; e < TPW * H * 16; e += 256) {
      int i = e >> 7;
      int h = (e >> 4) & 7;
      int cc = e & 15;
      sZt[e] = Z[(nbase + i) * (H * C) + (size_t)h * C + c0 + cc];
    }
    __syncthreads();
#pragma unroll
    for (int cc = 0; cc < 16; ++cc) {
      float w0 = sWtile[cc * C + cp0 + 0], w1 = sWtile[cc * C + cp0 + 1],
            w2 = sWtile[cc * C + cp0 + 2], w3 = sWtile[cc * C + cp0 + 3],
            w4 = sWtile[cc * C + cp0 + 4];
#pragma unroll
      for (int t4 = 0; t4 < 4; ++t4) {
        float zv = __bfloat162float(sZt[((i0 + t4) * H + h1) * 16 + cc]);
        acc[t4][0] += zv * w0; acc[t4][1] += zv * w1; acc[t4][2] += zv * w2;
        acc[t4][3] += zv * w3; acc[t4][4] += zv * w4;
      }
    }
    __syncthreads();
  }
#pragma unroll
  for (int t4 = 0; t4 < 4; ++t4)
#pragma unroll
    for (int j = 0; j < 5; ++j)
      sCtx[(i0 + t4) * C + cp0 + j] = acc[t4][j];
  __syncthreads();
  float oacc[4][5] = {};
  for (int c0 = 0; c0 < C; c0 += 16) {
    for (int e = tid; e < 16 * C; e += 256)
      sWtile[e] = Wo[(size_t)(c0 + e / C) * C + (e - (e / C) * C)];
    __syncthreads();
#pragma unroll
    for (int cc = 0; cc < 16; ++cc) {
      float w0 = sWtile[cc * C + cp0 + 0], w1 = sWtile[cc * C + cp0 + 1],
            w2 = sWtile[cc * C + cp0 + 2], w3 = sWtile[cc * C + cp0 + 3],
            w4 = sWtile[cc * C + cp0 + 4];
#pragma unroll
      for (int t4 = 0; t4 < 4; ++t4) {
        float cv = sCtx[(i0 + t4) * C + c0 + cc];
        oacc[t4][0] += cv * w0; oacc[t4][1] += cv * w1; oacc[t4][2] += cv * w2;
        oacc[t4][3] += cv * w3; oacc[t4][4] += cv * w4;
      }
    }
    __syncthreads();
  }
#pragma unroll
  for (int t4 = 0; t4 < 4; ++t4)
#pragma unroll
    for (int j = 0; j < 5; ++j)
      out[(nbase + i0 + t4) * C + cp0 + j] = oacc[t4][j] + bo[cp0 + j];
}

// ---------------------------------------------------------------------------
extern "C" void kernel_launch(void* const* d_in, const int* in_sizes, int n_in,
                              void* d_out, int out_size, void* d_ws, size_t ws_size,
                              hipStream_t stream) {
  const float* X      = (const float*)d_in[0];
  const float* cached = (const float*)d_in[1];
  const float* Wq     = (const float*)d_in[2];
  const float* Wk     = (const float*)d_in[3];
  const float* Wv     = (const float*)d_in[4];
  const float* Wo     = (const float*)d_in[5];
  const float* bo     = (const float*)d_in[6];
  (void)in_sizes; (void)n_in; (void)out_size; (void)ws_size;

  char* ws = (char*)d_ws;
  // layout (bytes):
  //  idx   : [0, 524288)
  //  Ksel  : [524288, 94896128)            16384*9*320 bf16
  //  Q     : [94896128, 115867648)         16384*320 f32
  //  tables: [115867648, 115879168)        2*1440 f32
  //  WkT   : [115879168, 116288768)        320*320 f32
  //  Z     : [116288768, 200174848)        16384*8*320 bf16
  int* idxb             = (int*)(ws + 0);
  __hip_bfloat16* Ksel  = (__hip_bfloat16*)(ws + 524288);
  float* Qm             = (float*)(ws + 94896128);
  float* cosT           = (float*)(ws + 115867648);
  float* sinT           = (float*)(ws + 115867648 + 5760);
  float* WkT            = (float*)(ws + 115879168);
  __hip_bfloat16* Z     = (__hip_bfloat16*)(ws + 116288768);

  k_tables<<<dim3(6), 256, 0, stream>>>(cosT, sinT);
  k_wkT<<<dim3(400), 256, 0, stream>>>(Wk, WkT);
  k_qgemm<<<dim3(256, 5), 256, 0, stream>>>(X, Wq, Qm);
  k_scoresel<<<dim3(NTOK), 256, 0, stream>>>(cached, Qm, WkT, idxb);
  k_kselgemm<<<dim3(2304, 5), 256, 0, stream>>>(X, cached, idxb, Wk, Ksel);
  k_attn<<<dim3(NTOK), 256, 0, stream>>>(X, cached, Qm, Ksel, idxb, cosT, sinT, Z);
  k_ctxout<<<dim3(NTOK / TPW), 256, 0, stream>>>(Z, Wv, Wo, bo, (float*)d_out);
}

// Round 3
// 3268.882 us; speedup vs baseline: 7.4757x; 7.4757x over previous
//
#include <hip/hip_runtime.h>
#include <hip/hip_bf16.h>
#include <math.h>

#define C 320
#define P 32
#define H 8
#define DH 40
#define RSEL 8
#define NINE 9
#define NTOK 16384
#define TPW 16
#define SLAB 2048   // tokens per k_past slab
#define NSLAB 8

// ---------------------------------------------------------------------------
// K0b: rope tables for positions 0..8, pair index 0..159 (fp32 storage)
// ---------------------------------------------------------------------------
__global__ __launch_bounds__(256) void k_tables(float* __restrict__ cosT,
                                                float* __restrict__ sinT) {
  int e = blockIdx.x * 256 + threadIdx.x;
  if (e >= NINE * 160) return;
  int l = e / 160, ii = e - l * 160;
  double inv = pow(10000.0, -(double)(2 * ii) / (double)C);
  double ang = (double)l * inv;
  cosT[e] = (float)cos(ang);
  sinT[e] = (float)sin(ang);
}

// ---------------------------------------------------------------------------
// K1b: Q = X @ Wq  (fp32), M=16384 N=320 K=320. grid (256,5), 64x64 tile BK=16
// (byte-identical to round 2 -> identical q rounding)
// ---------------------------------------------------------------------------
__global__ __launch_bounds__(256) void k_qgemm(const float* __restrict__ X,
                                               const float* __restrict__ W,
                                               float* __restrict__ Qo) {
  __shared__ float As[16][66];
  __shared__ float Bs[16][64];
  int tid = threadIdx.x;
  int m0 = blockIdx.x * 64, n0 = blockIdx.y * 64;
  int tm = (tid >> 4) << 2, tn = (tid & 15) << 2;
  int mA = tid >> 2, k4 = (tid & 3) << 2;
  int kB = tid >> 6, nB = tid & 63;
  float acc[4][4] = {};
  for (int k0 = 0; k0 < C; k0 += 16) {
    float4 av = *(const float4*)(X + (size_t)(m0 + mA) * C + k0 + k4);
    As[k4 + 0][mA] = av.x; As[k4 + 1][mA] = av.y; As[k4 + 2][mA] = av.z; As[k4 + 3][mA] = av.w;
#pragma unroll
    for (int j = 0; j < 4; ++j)
      Bs[kB + 4 * j][nB] = W[(size_t)(k0 + kB + 4 * j) * C + n0 + nB];
    __syncthreads();
#pragma unroll
    for (int kk = 0; kk < 16; ++kk) {
      float a0 = As[kk][tm + 0], a1 = As[kk][tm + 1], a2 = As[kk][tm + 2], a3 = As[kk][tm + 3];
      float b0 = Bs[kk][tn + 0], b1 = Bs[kk][tn + 1], b2 = Bs[kk][tn + 2], b3 = Bs[kk][tn + 3];
      acc[0][0] += a0 * b0; acc[0][1] += a0 * b1; acc[0][2] += a0 * b2; acc[0][3] += a0 * b3;
      acc[1][0] += a1 * b0; acc[1][1] += a1 * b1; acc[1][2] += a1 * b2; acc[1][3] += a1 * b3;
      acc[2][0] += a2 * b0; acc[2][1] += a2 * b1; acc[2][2] += a2 * b2; acc[2][3] += a2 * b3;
      acc[3][0] += a3 * b0; acc[3][1] += a3 * b1; acc[3][2] += a3 * b2; acc[3][3] += a3 * b3;
    }
    __syncthreads();
  }
#pragma unroll
  for (int i = 0; i < 4; ++i)
#pragma unroll
    for (int j = 0; j < 4; ++j)
      Qo[(size_t)(m0 + tm + i) * C + n0 + tn + j] = acc[i][j];
}

// ---------------------------------------------------------------------------
// K2a: k_past slab GEMM: Cc[m][cp] = sum_b A[m][b]*Wk[b][cp]
// M = SLAB*32 rows, N = 320, K = 320.  Tile 128x64, BK=16, thread tile 8x4.
// BIT-EXACTNESS: per output, k processed in ascending aligned 4-groups with
// kk DESCENDING inside each group, fmaf only — identical to round-2's
// fmaf(r.x,w.x,fmaf(r.y,w.y,fmaf(r.z,w.z,fmaf(r.w,w.w,acc)))) chain.
// grid (5, M/128): n-index fast so the A slab streams from HBM once.
// ---------------------------------------------------------------------------
__global__ __launch_bounds__(256) void k_kpast(const float* __restrict__ A,
                                               const float* __restrict__ Wk,
                                               float* __restrict__ Cc) {
  __shared__ float As[16][128];  // [k][m]
  __shared__ float Bs[16][64];   // [k][n]
  int tid = threadIdx.x;
  int n0 = blockIdx.x * 64;
  int m0 = blockIdx.y * 128;
  int tm = (tid >> 4) * 8;       // 0..120
  int tn = (tid & 15) * 4;       // 0..60
  int rA = tid >> 1;             // 0..127
  int cA = (tid & 1) * 8;        // 0 or 8
  int rB = tid >> 4;             // 0..15
  int cB = (tid & 15) * 4;       // 0..60
  float acc[8][4] = {};
  for (int k0 = 0; k0 < C; k0 += 16) {
    float4 a1 = *(const float4*)(A + (size_t)(m0 + rA) * C + k0 + cA);
    float4 a2 = *(const float4*)(A + (size_t)(m0 + rA) * C + k0 + cA + 4);
    As[cA + 0][rA] = a1.x; As[cA + 1][rA] = a1.y;
    As[cA + 2][rA] = a1.z; As[cA + 3][rA] = a1.w;
    As[cA + 4][rA] = a2.x; As[cA + 5][rA] = a2.y;
    As[cA + 6][rA] = a2.z; As[cA + 7][rA] = a2.w;
    *(float4*)&Bs[rB][cB] = *(const float4*)(Wk + (size_t)(k0 + rB) * C + n0 + cB);
    __syncthreads();
#pragma unroll
    for (int g = 0; g < 16; g += 4) {
#pragma unroll
      for (int kd = 3; kd >= 0; --kd) {
        int kk = g + kd;
        float4 aL = *(const float4*)&As[kk][tm];
        float4 aH = *(const float4*)&As[kk][tm + 4];
        float4 bV = *(const float4*)&Bs[kk][tn];
        float a[8] = {aL.x, aL.y, aL.z, aL.w, aH.x, aH.y, aH.z, aH.w};
        float b[4] = {bV.x, bV.y, bV.z, bV.w};
#pragma unroll
        for (int i = 0; i < 8; ++i)
#pragma unroll
          for (int j = 0; j < 4; ++j)
            acc[i][j] = fmaf(a[i], b[j], acc[i][j]);
      }
    }
    __syncthreads();
  }
#pragma unroll
  for (int i = 0; i < 8; ++i)
    *(float4*)&Cc[(size_t)(m0 + tm + i) * C + n0 + tn] =
        make_float4(acc[i][0], acc[i][1], acc[i][2], acc[i][3]);
}

// ---------------------------------------------------------------------------
// K2b: score = kp . q (exact round-2 order) + exact top-8.
// thread (p = tid>>3, l8 = tid&7), j ascending, same shfl tree, same argmax.
// Pointers are pre-offset to the slab. grid SLAB blocks.
// ---------------------------------------------------------------------------
__global__ __launch_bounds__(256) void k_score2(const float* __restrict__ kpast,
                                                const float* __restrict__ Qm,
                                                int* __restrict__ idxb) {
  __shared__ float sQ[C];
  __shared__ float sS[P];
  __shared__ int sIdx[RSEL];
  int n = blockIdx.x;
  int tid = threadIdx.x;
  for (int c = tid; c < C; c += 256) sQ[c] = Qm[(size_t)n * C + c];
  __syncthreads();
  int p = tid >> 3, l8 = tid & 7;
  const float* kpr = kpast + ((size_t)n * P + p) * C + l8;
  float sc = 0.f;
#pragma unroll
  for (int j = 0; j < 40; ++j) sc = fmaf(sQ[8 * j + l8], kpr[8 * j], sc);
  sc += __shfl_down(sc, 4, 8);
  sc += __shfl_down(sc, 2, 8);
  sc += __shfl_down(sc, 1, 8);
  if (l8 == 0) sS[p] = sc;
  __syncthreads();
  if (tid < 64) {
    float s = (tid < P) ? sS[tid] : -1e30f;
    int pi = (tid < P) ? tid : 9999;
    for (int r = 0; r < RSEL; ++r) {
      float bs = s; int bp = pi;
      for (int d = 1; d < 64; d <<= 1) {
        float os = __shfl_xor(bs, d);
        int op = __shfl_xor(bp, d);
        if (os > bs || (os == bs && op < bp)) { bs = os; bp = op; }
      }
      if (tid == 0) sIdx[r] = bp;
      if (pi == bp) s = -1e30f;
    }
  }
  __syncthreads();
  if (tid < RSEL) idxb[(size_t)n * RSEL + tid] = sIdx[tid];
}

// ---------------------------------------------------------------------------
// K3: Ksel = gather(rows) @ Wk -> bf16.  M=16384*9 rows: row l<8 = selected
// cached row, l==8 = x (k_now).  grid (2304, 5), 64x64 tile BK=16
// ---------------------------------------------------------------------------
__global__ __launch_bounds__(256) void k_kselgemm(const float* __restrict__ X,
                                                  const float* __restrict__ cached,
                                                  const int* __restrict__ idxb,
                                                  const float* __restrict__ Wk,
                                                  __hip_bfloat16* __restrict__ Ksel) {
  __shared__ float As[16][66];
  __shared__ float Bs[16][64];
  __shared__ const float* srow[64];
  int tid = threadIdx.x;
  int m0 = blockIdx.x * 64, n0 = blockIdx.y * 64;
  if (tid < 64) {
    int m = m0 + tid;
    int n = m / NINE, l = m - n * NINE;
    srow[tid] = (l < RSEL)
        ? cached + ((size_t)n * P + idxb[(size_t)n * RSEL + l]) * C
        : X + (size_t)n * C;
  }
  __syncthreads();
  int tm = (tid >> 4) << 2, tn = (tid & 15) << 2;
  int mA = tid >> 2, k4 = (tid & 3) << 2;
  int kB = tid >> 6, nB = tid & 63;
  float acc[4][4] = {};
  for (int k0 = 0; k0 < C; k0 += 16) {
    float4 av = *(const float4*)(srow[mA] + k0 + k4);
    As[k4 + 0][mA] = av.x; As[k4 + 1][mA] = av.y; As[k4 + 2][mA] = av.z; As[k4 + 3][mA] = av.w;
#pragma unroll
    for (int j = 0; j < 4; ++j)
      Bs[kB + 4 * j][nB] = Wk[(size_t)(k0 + kB + 4 * j) * C + n0 + nB];
    __syncthreads();
#pragma unroll
    for (int kk = 0; kk < 16; ++kk) {
      float a0 = As[kk][tm + 0], a1 = As[kk][tm + 1], a2 = As[kk][tm + 2], a3 = As[kk][tm + 3];
      float b0 = Bs[kk][tn + 0], b1 = Bs[kk][tn + 1], b2 = Bs[kk][tn + 2], b3 = Bs[kk][tn + 3];
      acc[0][0] += a0 * b0; acc[0][1] += a0 * b1; acc[0][2] += a0 * b2; acc[0][3] += a0 * b3;
      acc[1][0] += a1 * b0; acc[1][1] += a1 * b1; acc[1][2] += a1 * b2; acc[1][3] += a1 * b3;
      acc[2][0] += a2 * b0; acc[2][1] += a2 * b1; acc[2][2] += a2 * b2; acc[2][3] += a2 * b3;
      acc[3][0] += a3 * b0; acc[3][1] += a3 * b1; acc[3][2] += a3 * b2; acc[3][3] += a3 * b3;
    }
    __syncthreads();
  }
#pragma unroll
  for (int i = 0; i < 4; ++i)
#pragma unroll
    for (int j = 0; j < 4; ++j)
      Ksel[(size_t)(m0 + tm + i) * C + n0 + tn + j] = __float2bfloat16(acc[i][j]);
}

// ---------------------------------------------------------------------------
// K4a: per-token attention: rope(Ksel), logits, softmax, z = sum_l w*row_l
// writes Z bf16 [n][h][c].  grid 16384, 256 threads
// ---------------------------------------------------------------------------
__global__ __launch_bounds__(256) void k_attn(const float* __restrict__ X,
                                              const float* __restrict__ cached,
                                              const float* __restrict__ Qm,
                                              const __hip_bfloat16* __restrict__ Ksel,
                                              const int* __restrict__ idxb,
                                              const float* __restrict__ cosT,
                                              const float* __restrict__ sinT,
                                              __hip_bfloat16* __restrict__ Z) {
  __shared__ float sK[NINE * C];
  __shared__ float sRows[NINE * C];
  __shared__ float sQ[C];
  __shared__ float sLog[H * NINE];
  __shared__ float sWgt[H * NINE];
  __shared__ int sIdx[RSEL];
  int n = blockIdx.x;
  int tid = threadIdx.x;
  if (tid < RSEL) sIdx[tid] = idxb[(size_t)n * RSEL + tid];
  for (int c = tid; c < C; c += 256) sQ[c] = Qm[(size_t)n * C + c];
  __syncthreads();
  for (int e = tid; e < NINE * C; e += 256) {
    int l = e / C, c = e - l * C;
    sK[e] = __bfloat162float(Ksel[((size_t)n * NINE + l) * C + c]);
    const float* src = (l < RSEL)
        ? cached + ((size_t)n * P + sIdx[l]) * C
        : X + (size_t)n * C;
    sRows[e] = src[c];
  }
  __syncthreads();
  for (int e = tid; e < NINE * 160; e += 256) {
    int l = e / 160, ii = e - l * 160;
    float cs = cosT[e], sn = sinT[e];
    float ev = sK[l * C + 2 * ii], ov = sK[l * C + 2 * ii + 1];
    sK[l * C + 2 * ii]     = ev * cs - ov * sn;
    sK[l * C + 2 * ii + 1] = ev * sn + ov * cs;
  }
  __syncthreads();
  if (tid < H * NINE) {
    int h = tid / NINE, l = tid - h * NINE;
    const float* qh = sQ + h * DH;
    const float* kh = sK + l * C + h * DH;
    float a = 0.f;
    for (int d = 0; d < DH; ++d) a += qh[d] * kh[d];
    sLog[tid] = a * 0.15811388300841897f; // 40^-0.5
  }
  __syncthreads();
  if (tid < H) {
    float m = -1e30f;
    for (int l = 0; l < NINE; ++l) m = fmaxf(m, sLog[tid * NINE + l]);
    float w[NINE];
    float s = 0.f;
    for (int l = 0; l < NINE; ++l) { w[l] = expf(sLog[tid * NINE + l] - m); s += w[l]; }
    float inv = 1.f / s;
    for (int l = 0; l < NINE; ++l) sWgt[tid * NINE + l] = w[l] * inv;
  }
  __syncthreads();
  for (int o = tid; o < H * C; o += 256) {
    int h = o / C, c = o - h * C;
    float a = 0.f;
#pragma unroll
    for (int l = 0; l < NINE; ++l) a += sWgt[h * NINE + l] * sRows[l * C + c];
    Z[(size_t)n * (H * C) + o] = __float2bfloat16(a);
  }
}

// ---------------------------------------------------------------------------
// K4b: ctx[i][cp] = sum_c Z[i][h(cp)][c]*Wv[c][cp]; out = ctx@Wo + bo
// grid 1024 (16 tokens each), 256 threads; micro-tile 4 tokens x 5 cols
// ---------------------------------------------------------------------------
__global__ __launch_bounds__(256) void k_ctxout(const __hip_bfloat16* __restrict__ Z,
                                                const float* __restrict__ Wv,
                                                const float* __restrict__ Wo,
                                                const float* __restrict__ bo,
                                                float* __restrict__ out) {
  __shared__ float sWtile[16 * C];
  __shared__ __hip_bfloat16 sZt[TPW * H * 16];
  __shared__ float sCtx[TPW * C];
  int tid = threadIdx.x;
  size_t nbase = (size_t)blockIdx.x * TPW;
  int i0 = (tid >> 6) << 2;
  int tc = tid & 63;
  int cp0 = tc * 5;
  int h1 = cp0 / DH;
  float acc[4][5] = {};
  for (int c0 = 0; c0 < C; c0 += 16) {
    for (int e = tid; e < 16 * C; e += 256)
      sWtile[e] = Wv[(size_t)(c0 + e / C) * C + (e - (e / C) * C)];
    for (int e = tid; e < TPW * H * 16; e += 256) {
      int i = e >> 7;
      int h = (e >> 4) & 7;
      int cc = e & 15;
      sZt[e] = Z[(nbase + i) * (H * C) + (size_t)h * C + c0 + cc];
    }
    __syncthreads();
#pragma unroll
    for (int cc = 0; cc < 16; ++cc) {
      float w0 = sWtile[cc * C + cp0 + 0], w1 = sWtile[cc * C + cp0 + 1],
            w2 = sWtile[cc * C + cp0 + 2], w3 = sWtile[cc * C + cp0 + 3],
            w4 = sWtile[cc * C + cp0 + 4];
#pragma unroll
      for (int t4 = 0; t4 < 4; ++t4) {
        float zv = __bfloat162float(sZt[((i0 + t4) * H + h1) * 16 + cc]);
        acc[t4][0] += zv * w0; acc[t4][1] += zv * w1; acc[t4][2] += zv * w2;
        acc[t4][3] += zv * w3; acc[t4][4] += zv * w4;
      }
    }
    __syncthreads();
  }
#pragma unroll
  for (int t4 = 0; t4 < 4; ++t4)
#pragma unroll
    for (int j = 0; j < 5; ++j)
      sCtx[(i0 + t4) * C + cp0 + j] = acc[t4][j];
  __syncthreads();
  float oacc[4][5] = {};
  for (int c0 = 0; c0 < C; c0 += 16) {
    for (int e = tid; e < 16 * C; e += 256)
      sWtile[e] = Wo[(size_t)(c0 + e / C) * C + (e - (e / C) * C)];
    __syncthreads();
#pragma unroll
    for (int cc = 0; cc < 16; ++cc) {
      float w0 = sWtile[cc * C + cp0 + 0], w1 = sWtile[cc * C + cp0 + 1],
            w2 = sWtile[cc * C + cp0 + 2], w3 = sWtile[cc * C + cp0 + 3],
            w4 = sWtile[cc * C + cp0 + 4];
#pragma unroll
      for (int t4 = 0; t4 < 4; ++t4) {
        float cv = sCtx[(i0 + t4) * C + c0 + cc];
        oacc[t4][0] += cv * w0; oacc[t4][1] += cv * w1; oacc[t4][2] += cv * w2;
        oacc[t4][3] += cv * w3; oacc[t4][4] += cv * w4;
      }
    }
    __syncthreads();
  }
#pragma unroll
  for (int t4 = 0; t4 < 4; ++t4)
#pragma unroll
    for (int j = 0; j < 5; ++j)
      out[(nbase + i0 + t4) * C + cp0 + j] = oacc[t4][j] + bo[cp0 + j];
}

// ---------------------------------------------------------------------------
extern "C" void kernel_launch(void* const* d_in, const int* in_sizes, int n_in,
                              void* d_out, int out_size, void* d_ws, size_t ws_size,
                              hipStream_t stream) {
  const float* X      = (const float*)d_in[0];
  const float* cached = (const float*)d_in[1];
  const float* Wq     = (const float*)d_in[2];
  const float* Wk     = (const float*)d_in[3];
  const float* Wv     = (const float*)d_in[4];
  const float* Wo     = (const float*)d_in[5];
  const float* bo     = (const float*)d_in[6];
  (void)in_sizes; (void)n_in; (void)out_size; (void)ws_size;

  char* ws = (char*)d_ws;
  // layout (bytes):
  //  idx   : [0, 524288)
  //  Ksel  : [524288, 94896128)   16384*9*320 bf16 — ALSO k_past slab buffer
  //          (84MB slab dead before Ksel is written; stream-serialized)
  //  Q     : [94896128, 115867648)  16384*320 f32
  //  tables: [115867648, 115879168) 2*1440 f32
  //  Z     : [116288768, 200174848) 16384*8*320 bf16
  int* idxb             = (int*)(ws + 0);
  __hip_bfloat16* Ksel  = (__hip_bfloat16*)(ws + 524288);
  float* kpast          = (float*)(ws + 524288);
  float* Qm             = (float*)(ws + 94896128);
  float* cosT           = (float*)(ws + 115867648);
  float* sinT           = (float*)(ws + 115867648 + 5760);
  __hip_bfloat16* Z     = (__hip_bfloat16*)(ws + 116288768);

  k_tables<<<dim3(6), 256, 0, stream>>>(cosT, sinT);
  k_qgemm<<<dim3(256, 5), 256, 0, stream>>>(X, Wq, Qm);
  for (int s = 0; s < NSLAB; ++s) {
    k_kpast<<<dim3(5, SLAB * P / 128), 256, 0, stream>>>(
        cached + (size_t)s * SLAB * P * C, Wk, kpast);
    k_score2<<<dim3(SLAB), 256, 0, stream>>>(
        kpast, Qm + (size_t)s * SLAB * C, idxb + (size_t)s * SLAB * RSEL);
  }
  k_kselgemm<<<dim3(2304, 5), 256, 0, stream>>>(X, cached, idxb, Wk, Ksel);
  k_attn<<<dim3(NTOK), 256, 0, stream>>>(X, cached, Qm, Ksel, idxb, cosT, sinT, Z);
  k_ctxout<<<dim3(NTOK / TPW), 256, 0, stream>>>(Z, Wv, Wo, bo, (float*)d_out);
}

// Round 4
// 3263.070 us; speedup vs baseline: 7.4890x; 1.0018x over previous
//
#include <hip/hip_runtime.h>
#include <hip/hip_bf16.h>
#include <math.h>

#define C 320
#define P 32
#define H 8
#define DH 40
#define RSEL 8
#define NINE 9
#define NTOK 16384
#define TPW 16
#define SLAB 2048   // tokens per k_past slab
#define NSLAB 8

static __device__ __forceinline__ unsigned short f2bf_us(float x) {
  __hip_bfloat16 h = __float2bfloat16(x);
  return *reinterpret_cast<unsigned short*>(&h);
}

// ---------------------------------------------------------------------------
// K0b: rope tables for positions 0..8, pair index 0..159 (fp32 storage)
// ---------------------------------------------------------------------------
__global__ __launch_bounds__(256) void k_tables(float* __restrict__ cosT,
                                                float* __restrict__ sinT) {
  int e = blockIdx.x * 256 + threadIdx.x;
  if (e >= NINE * 160) return;
  int l = e / 160, ii = e - l * 160;
  double inv = pow(10000.0, -(double)(2 * ii) / (double)C);
  double ang = (double)l * inv;
  cosT[e] = (float)cos(ang);
  sinT[e] = (float)sin(ang);
}

// ---------------------------------------------------------------------------
// K1b: Q = X @ Wq  (fp32). BIT-FROZEN (feeds the score path). Do not touch.
// ---------------------------------------------------------------------------
__global__ __launch_bounds__(256) void k_qgemm(const float* __restrict__ X,
                                               const float* __restrict__ W,
                                               float* __restrict__ Qo) {
  __shared__ float As[16][66];
  __shared__ float Bs[16][64];
  int tid = threadIdx.x;
  int m0 = blockIdx.x * 64, n0 = blockIdx.y * 64;
  int tm = (tid >> 4) << 2, tn = (tid & 15) << 2;
  int mA = tid >> 2, k4 = (tid & 3) << 2;
  int kB = tid >> 6, nB = tid & 63;
  float acc[4][4] = {};
  for (int k0 = 0; k0 < C; k0 += 16) {
    float4 av = *(const float4*)(X + (size_t)(m0 + mA) * C + k0 + k4);
    As[k4 + 0][mA] = av.x; As[k4 + 1][mA] = av.y; As[k4 + 2][mA] = av.z; As[k4 + 3][mA] = av.w;
#pragma unroll
    for (int j = 0; j < 4; ++j)
      Bs[kB + 4 * j][nB] = W[(size_t)(k0 + kB + 4 * j) * C + n0 + nB];
    __syncthreads();
#pragma unroll
    for (int kk = 0; kk < 16; ++kk) {
      float a0 = As[kk][tm + 0], a1 = As[kk][tm + 1], a2 = As[kk][tm + 2], a3 = As[kk][tm + 3];
      float b0 = Bs[kk][tn + 0], b1 = Bs[kk][tn + 1], b2 = Bs[kk][tn + 2], b3 = Bs[kk][tn + 3];
      acc[0][0] += a0 * b0; acc[0][1] += a0 * b1; acc[0][2] += a0 * b2; acc[0][3] += a0 * b3;
      acc[1][0] += a1 * b0; acc[1][1] += a1 * b1; acc[1][2] += a1 * b2; acc[1][3] += a1 * b3;
      acc[2][0] += a2 * b0; acc[2][1] += a2 * b1; acc[2][2] += a2 * b2; acc[2][3] += a2 * b3;
      acc[3][0] += a3 * b0; acc[3][1] += a3 * b1; acc[3][2] += a3 * b2; acc[3][3] += a3 * b3;
    }
    __syncthreads();
  }
#pragma unroll
  for (int i = 0; i < 4; ++i)
#pragma unroll
    for (int j = 0; j < 4; ++j)
      Qo[(size_t)(m0 + tm + i) * C + n0 + tn + j] = acc[i][j];
}

// ---------------------------------------------------------------------------
// K2a: k_past slab GEMM: Cc[m][cp] = sum_b A[m][b]*Wk[b][cp]
// Tile 256x64, BK=16, thread tile 8x8 (64 FMA per 4 ds_read_b128).
// BIT-EXACT per-output order: ascending aligned 4-groups, kk DESCENDING
// inside each group, fmaf only — identical to the frozen round-2 chain.
// grid (5, M/256): n fast so A-tile is L2/L3-hot across the 5 n-blocks.
// ---------------------------------------------------------------------------
__global__ __launch_bounds__(256) void k_kpast(const float* __restrict__ A,
                                               const float* __restrict__ Wk,
                                               float* __restrict__ Cc) {
  __shared__ float As[16][256];  // [k][m]
  __shared__ float Bs[16][64];   // [k][n]
  int tid = threadIdx.x;
  int n0 = blockIdx.x * 64;
  int m0 = blockIdx.y * 256;
  int tm = (tid >> 3) * 8;       // 0..248
  int tn = (tid & 7) * 8;        // 0..56
  int kB = tid >> 4, cB = (tid & 15) * 4;
  float acc[8][8] = {};
  for (int k0 = 0; k0 < C; k0 += 16) {
    const float* ap = A + (size_t)(m0 + tid) * C + k0;
    float4 a0 = *(const float4*)(ap + 0);
    float4 a1 = *(const float4*)(ap + 4);
    float4 a2 = *(const float4*)(ap + 8);
    float4 a3 = *(const float4*)(ap + 12);
    As[0][tid] = a0.x;  As[1][tid] = a0.y;  As[2][tid] = a0.z;  As[3][tid] = a0.w;
    As[4][tid] = a1.x;  As[5][tid] = a1.y;  As[6][tid] = a1.z;  As[7][tid] = a1.w;
    As[8][tid] = a2.x;  As[9][tid] = a2.y;  As[10][tid] = a2.z; As[11][tid] = a2.w;
    As[12][tid] = a3.x; As[13][tid] = a3.y; As[14][tid] = a3.z; As[15][tid] = a3.w;
    *(float4*)&Bs[kB][cB] = *(const float4*)(Wk + (size_t)(k0 + kB) * C + n0 + cB);
    __syncthreads();
#pragma unroll
    for (int g = 0; g < 16; g += 4) {
#pragma unroll
      for (int kd = 3; kd >= 0; --kd) {
        int kk = g + kd;
        float4 aL = *(const float4*)&As[kk][tm];
        float4 aH = *(const float4*)&As[kk][tm + 4];
        float4 bL = *(const float4*)&Bs[kk][tn];
        float4 bH = *(const float4*)&Bs[kk][tn + 4];
        float a[8] = {aL.x, aL.y, aL.z, aL.w, aH.x, aH.y, aH.z, aH.w};
        float b[8] = {bL.x, bL.y, bL.z, bL.w, bH.x, bH.y, bH.z, bH.w};
#pragma unroll
        for (int i = 0; i < 8; ++i)
#pragma unroll
          for (int j = 0; j < 8; ++j)
            acc[i][j] = fmaf(a[i], b[j], acc[i][j]);
      }
    }
    __syncthreads();
  }
#pragma unroll
  for (int i = 0; i < 8; ++i) {
    float* cp = Cc + (size_t)(m0 + tm + i) * C + n0 + tn;
    *(float4*)(cp + 0) = make_float4(acc[i][0], acc[i][1], acc[i][2], acc[i][3]);
    *(float4*)(cp + 4) = make_float4(acc[i][4], acc[i][5], acc[i][6], acc[i][7]);
  }
}

// ---------------------------------------------------------------------------
// K2b: score = kp . q + exact top-8. BIT-FROZEN. grid SLAB blocks.
// ---------------------------------------------------------------------------
__global__ __launch_bounds__(256) void k_score2(const float* __restrict__ kpast,
                                                const float* __restrict__ Qm,
                                                int* __restrict__ idxb) {
  __shared__ float sQ[C];
  __shared__ float sS[P];
  __shared__ int sIdx[RSEL];
  int n = blockIdx.x;
  int tid = threadIdx.x;
  for (int c = tid; c < C; c += 256) sQ[c] = Qm[(size_t)n * C + c];
  __syncthreads();
  int p = tid >> 3, l8 = tid & 7;
  const float* kpr = kpast + ((size_t)n * P + p) * C + l8;
  float sc = 0.f;
#pragma unroll
  for (int j = 0; j < 40; ++j) sc = fmaf(sQ[8 * j + l8], kpr[8 * j], sc);
  sc += __shfl_down(sc, 4, 8);
  sc += __shfl_down(sc, 2, 8);
  sc += __shfl_down(sc, 1, 8);
  if (l8 == 0) sS[p] = sc;
  __syncthreads();
  if (tid < 64) {
    float s = (tid < P) ? sS[tid] : -1e30f;
    int pi = (tid < P) ? tid : 9999;
    for (int r = 0; r < RSEL; ++r) {
      float bs = s; int bp = pi;
      for (int d = 1; d < 64; d <<= 1) {
        float os = __shfl_xor(bs, d);
        int op = __shfl_xor(bp, d);
        if (os > bs || (os == bs && op < bp)) { bs = os; bp = op; }
      }
      if (tid == 0) sIdx[r] = bp;
      if (pi == bp) s = -1e30f;
    }
  }
  __syncthreads();
  if (tid < RSEL) idxb[(size_t)n * RSEL + tid] = sIdx[tid];
}

// ---------------------------------------------------------------------------
// K3: Ksel = gather(rows) @ Wk -> bf16.  Full-N tile: 64 rows x 320 cols,
// BK=16, thread tile 4m x 20n (5 x float4). Gathered rows read ONCE.
// grid 2304 blocks. (Not bit-frozen: bf16 output, tolerance downstream.)
// ---------------------------------------------------------------------------
__global__ __launch_bounds__(256) void k_kselgemm(const float* __restrict__ X,
                                                  const float* __restrict__ cached,
                                                  const int* __restrict__ idxb,
                                                  const float* __restrict__ Wk,
                                                  __hip_bfloat16* __restrict__ Ksel) {
  __shared__ float As[16][64];
  __shared__ float Bs[16][320];
  __shared__ const float* srow[64];
  int tid = threadIdx.x;
  int m0 = blockIdx.x * 64;
  if (tid < 64) {
    int m = m0 + tid;
    int n = m / NINE, l = m - n * NINE;
    srow[tid] = (l < RSEL)
        ? cached + ((size_t)n * P + idxb[(size_t)n * RSEL + l]) * C
        : X + (size_t)n * C;
  }
  __syncthreads();
  int tm = (tid >> 4) * 4;        // 0..60
  int tn0 = (tid & 15) * 4;       // 0..60; cols tn0 + 64*j
  int rA = tid >> 2, cA = (tid & 3) * 4;
  float acc[4][5][4] = {};
  for (int k0 = 0; k0 < C; k0 += 16) {
    float4 av = *(const float4*)(srow[rA] + k0 + cA);
    As[cA + 0][rA] = av.x; As[cA + 1][rA] = av.y;
    As[cA + 2][rA] = av.z; As[cA + 3][rA] = av.w;
#pragma unroll
    for (int j = 0; j < 5; ++j) {
      int idx = tid + 256 * j;          // 0..1279
      int kb = idx / 80, cb = (idx - kb * 80) * 4;
      *(float4*)&Bs[kb][cb] = *(const float4*)(Wk + (size_t)(k0 + kb) * C + cb);
    }
    __syncthreads();
#pragma unroll
    for (int kk = 0; kk < 16; ++kk) {
      float4 a = *(const float4*)&As[kk][tm];
      float am[4] = {a.x, a.y, a.z, a.w};
#pragma unroll
      for (int j = 0; j < 5; ++j) {
        float4 b = *(const float4*)&Bs[kk][tn0 + 64 * j];
#pragma unroll
        for (int i = 0; i < 4; ++i) {
          acc[i][j][0] = fmaf(am[i], b.x, acc[i][j][0]);
          acc[i][j][1] = fmaf(am[i], b.y, acc[i][j][1]);
          acc[i][j][2] = fmaf(am[i], b.z, acc[i][j][2]);
          acc[i][j][3] = fmaf(am[i], b.w, acc[i][j][3]);
        }
      }
    }
    __syncthreads();
  }
#pragma unroll
  for (int i = 0; i < 4; ++i)
#pragma unroll
    for (int j = 0; j < 5; ++j) {
      ushort4 pk;
      pk.x = f2bf_us(acc[i][j][0]);
      pk.y = f2bf_us(acc[i][j][1]);
      pk.z = f2bf_us(acc[i][j][2]);
      pk.w = f2bf_us(acc[i][j][3]);
      *(ushort4*)&Ksel[(size_t)(m0 + tm + i) * C + tn0 + 64 * j] = pk;
    }
}

// ---------------------------------------------------------------------------
// K4a: per-token attention: rope(Ksel), logits, softmax, z = sum_l w*row_l
// writes Z bf16 [n][h][c].  grid 16384, 256 threads
// ---------------------------------------------------------------------------
__global__ __launch_bounds__(256) void k_attn(const float* __restrict__ X,
                                              const float* __restrict__ cached,
                                              const float* __restrict__ Qm,
                                              const __hip_bfloat16* __restrict__ Ksel,
                                              const int* __restrict__ idxb,
                                              const float* __restrict__ cosT,
                                              const float* __restrict__ sinT,
                                              __hip_bfloat16* __restrict__ Z) {
  __shared__ float sK[NINE * C];
  __shared__ float sRows[NINE * C];
  __shared__ float sQ[C];
  __shared__ float sLog[H * NINE];
  __shared__ float sWgt[H * NINE];
  __shared__ int sIdx[RSEL];
  int n = blockIdx.x;
  int tid = threadIdx.x;
  if (tid < RSEL) sIdx[tid] = idxb[(size_t)n * RSEL + tid];
  for (int c = tid; c < C; c += 256) sQ[c] = Qm[(size_t)n * C + c];
  __syncthreads();
  for (int e = tid; e < NINE * C; e += 256) {
    int l = e / C, c = e - l * C;
    sK[e] = __bfloat162float(Ksel[((size_t)n * NINE + l) * C + c]);
    const float* src = (l < RSEL)
        ? cached + ((size_t)n * P + sIdx[l]) * C
        : X + (size_t)n * C;
    sRows[e] = src[c];
  }
  __syncthreads();
  for (int e = tid; e < NINE * 160; e += 256) {
    int l = e / 160, ii = e - l * 160;
    float cs = cosT[e], sn = sinT[e];
    float ev = sK[l * C + 2 * ii], ov = sK[l * C + 2 * ii + 1];
    sK[l * C + 2 * ii]     = ev * cs - ov * sn;
    sK[l * C + 2 * ii + 1] = ev * sn + ov * cs;
  }
  __syncthreads();
  if (tid < H * NINE) {
    int h = tid / NINE, l = tid - h * NINE;
    const float* qh = sQ + h * DH;
    const float* kh = sK + l * C + h * DH;
    float a = 0.f;
    for (int d = 0; d < DH; ++d) a += qh[d] * kh[d];
    sLog[tid] = a * 0.15811388300841897f; // 40^-0.5
  }
  __syncthreads();
  if (tid < H) {
    float m = -1e30f;
    for (int l = 0; l < NINE; ++l) m = fmaxf(m, sLog[tid * NINE + l]);
    float w[NINE];
    float s = 0.f;
    for (int l = 0; l < NINE; ++l) { w[l] = expf(sLog[tid * NINE + l] - m); s += w[l]; }
    float inv = 1.f / s;
    for (int l = 0; l < NINE; ++l) sWgt[tid * NINE + l] = w[l] * inv;
  }
  __syncthreads();
  for (int o = tid; o < H * C; o += 256) {
    int h = o / C, c = o - h * C;
    float a = 0.f;
#pragma unroll
    for (int l = 0; l < NINE; ++l) a += sWgt[h * NINE + l] * sRows[l * C + c];
    Z[(size_t)n * (H * C) + o] = __float2bfloat16(a);
  }
}

// ---------------------------------------------------------------------------
// K4b: ctx[i][cp] = sum_c Z[i][h(cp)][c]*Wv[c][cp]; out = ctx@Wo + bo
// grid 1024 (16 tokens each), 256 threads; micro-tile 4 tokens x 5 cols
// ---------------------------------------------------------------------------
__global__ __launch_bounds__(256) void k_ctxout(const __hip_bfloat16* __restrict__ Z,
                                                const float* __restrict__ Wv,
                                                const float* __restrict__ Wo,
                                                const float* __restrict__ bo,
                                                float* __restrict__ out) {
  __shared__ float sWtile[16 * C];
  __shared__ __hip_bfloat16 sZt[TPW * H * 16];
  __shared__ float sCtx[TPW * C];
  int tid = threadIdx.x;
  size_t nbase = (size_t)blockIdx.x * TPW;
  int i0 = (tid >> 6) << 2;
  int tc = tid & 63;
  int cp0 = tc * 5;
  int h1 = cp0 / DH;
  float acc[4][5] = {};
  for (int c0 = 0; c0 < C; c0 += 16) {
    for (int e = tid; e < 16 * C; e += 256)
      sWtile[e] = Wv[(size_t)(c0 + e / C) * C + (e - (e / C) * C)];
    for (int e = tid; e < TPW * H * 16; e += 256) {
      int i = e >> 7;
      int h = (e >> 4) & 7;
      int cc = e & 15;
      sZt[e] = Z[(nbase + i) * (H * C) + (size_t)h * C + c0 + cc];
    }
    __syncthreads();
#pragma unroll
    for (int cc = 0; cc < 16; ++cc) {
      float w0 = sWtile[cc * C + cp0 + 0], w1 = sWtile[cc * C + cp0 + 1],
            w2 = sWtile[cc * C + cp0 + 2], w3 = sWtile[cc * C + cp0 + 3],
            w4 = sWtile[cc * C + cp0 + 4];
#pragma unroll
      for (int t4 = 0; t4 < 4; ++t4) {
        float zv = __bfloat162float(sZt[((i0 + t4) * H + h1) * 16 + cc]);
        acc[t4][0] += zv * w0; acc[t4][1] += zv * w1; acc[t4][2] += zv * w2;
        acc[t4][3] += zv * w3; acc[t4][4] += zv * w4;
      }
    }
    __syncthreads();
  }
#pragma unroll
  for (int t4 = 0; t4 < 4; ++t4)
#pragma unroll
    for (int j = 0; j < 5; ++j)
      sCtx[(i0 + t4) * C + cp0 + j] = acc[t4][j];
  __syncthreads();
  float oacc[4][5] = {};
  for (int c0 = 0; c0 < C; c0 += 16) {
    for (int e = tid; e < 16 * C; e += 256)
      sWtile[e] = Wo[(size_t)(c0 + e / C) * C + (e - (e / C) * C)];
    __syncthreads();
#pragma unroll
    for (int cc = 0; cc < 16; ++cc) {
      float w0 = sWtile[cc * C + cp0 + 0], w1 = sWtile[cc * C + cp0 + 1],
            w2 = sWtile[cc * C + cp0 + 2], w3 = sWtile[cc * C + cp0 + 3],
            w4 = sWtile[cc * C + cp0 + 4];
#pragma unroll
      for (int t4 = 0; t4 < 4; ++t4) {
        float cv = sCtx[(i0 + t4) * C + c0 + cc];
        oacc[t4][0] += cv * w0; oacc[t4][1] += cv * w1; oacc[t4][2] += cv * w2;
        oacc[t4][3] += cv * w3; oacc[t4][4] += cv * w4;
      }
    }
    __syncthreads();
  }
#pragma unroll
  for (int t4 = 0; t4 < 4; ++t4)
#pragma unroll
    for (int j = 0; j < 5; ++j)
      out[(nbase + i0 + t4) * C + cp0 + j] = oacc[t4][j] + bo[cp0 + j];
}

// ---------------------------------------------------------------------------
extern "C" void kernel_launch(void* const* d_in, const int* in_sizes, int n_in,
                              void* d_out, int out_size, void* d_ws, size_t ws_size,
                              hipStream_t stream) {
  const float* X      = (const float*)d_in[0];
  const float* cached = (const float*)d_in[1];
  const float* Wq     = (const float*)d_in[2];
  const float* Wk     = (const float*)d_in[3];
  const float* Wv     = (const float*)d_in[4];
  const float* Wo     = (const float*)d_in[5];
  const float* bo     = (const float*)d_in[6];
  (void)in_sizes; (void)n_in; (void)out_size; (void)ws_size;

  char* ws = (char*)d_ws;
  // layout (bytes):
  //  idx   : [0, 524288)
  //  Ksel  : [524288, 94896128)   16384*9*320 bf16 — ALSO k_past slab buffer
  //          (84MB slab dead before Ksel is written; stream-serialized)
  //  Q     : [94896128, 115867648)  16384*320 f32
  //  tables: [115867648, 115879168) 2*1440 f32
  //  Z     : [116288768, 200174848) 16384*8*320 bf16
  int* idxb             = (int*)(ws + 0);
  __hip_bfloat16* Ksel  = (__hip_bfloat16*)(ws + 524288);
  float* kpast          = (float*)(ws + 524288);
  float* Qm             = (float*)(ws + 94896128);
  float* cosT           = (float*)(ws + 115867648);
  float* sinT           = (float*)(ws + 115867648 + 5760);
  __hip_bfloat16* Z     = (__hip_bfloat16*)(ws + 116288768);

  k_tables<<<dim3(6), 256, 0, stream>>>(cosT, sinT);
  k_qgemm<<<dim3(256, 5), 256, 0, stream>>>(X, Wq, Qm);
  for (int s = 0; s < NSLAB; ++s) {
    k_kpast<<<dim3(5, SLAB * P / 256), 256, 0, stream>>>(
        cached + (size_t)s * SLAB * P * C, Wk, kpast);
    k_score2<<<dim3(SLAB), 256, 0, stream>>>(
        kpast, Qm + (size_t)s * SLAB * C, idxb + (size_t)s * SLAB * RSEL);
  }
  k_kselgemm<<<dim3(2304), 256, 0, stream>>>(X, cached, idxb, Wk, Ksel);
  k_attn<<<dim3(NTOK), 256, 0, stream>>>(X, cached, Qm, Ksel, idxb, cosT, sinT, Z);
  k_ctxout<<<dim3(NTOK / TPW), 256, 0, stream>>>(Z, Wv, Wo, bo, (float*)d_out);
}